// Round 10
// baseline (250.232 us; speedup 1.0000x reference)
//
#include <hip/hip_runtime.h>
#include <hip/hip_bf16.h>

// InfoNCE: a[4096,512], p[4096,512], n[16384,512] f32 -> 4 f32 scalars.
// R14: TWO stream nodes (memset + one fused kernel). Cross-round accounting
//     shows ~28-30us per stream node (R13 4-node residual 118us; R11 2-node
//     55us) -- node count is the dominant remaining cost. R11's fused attempt
//     crawled because each block's grid barrier used __threadfence (agent
//     release/acquire -> buffer_wbl2 + buffer_inv per block = 64 L2 nukes per
//     XCD during the GEMM phase, killing B-panel reuse). R14 fuses WITHOUT
//     cache fences: all cross-phase data flows through the coherent point --
//     fp8 outputs via agent-scope RELAXED ATOMIC STORES (bypass non-coherent
//     L2; readers never cached those lines), S/colsums/lsum via device
//     atomicAdd + relaxed atomic loads. Barrier = syncthreads (drains vmcnt)
//     -> atomicAdd -> s_sleep spin. GEMM core = R9 verbatim (best measured).
//     Norm phase perfectly balanced: 6 rows per wave (1 anc, 1 pos, 4 neg).
// ws layout: a8(2MB) p8(2MB) n8(8MB) | S[4096] csA[8192] csP[8192] csN[8192]
//            lsum[1] pad[3] cnt[4]

#define D_DIM 512
#define B_ROWS 4096
#define P_ROWS 4096
#define N_ROWS 16384
#define INV_T 14.285714285714286f
#define EPS_L 1e-8f
#define CS_STRIDE 16
#define GRID 512

typedef unsigned char fp8_t;
typedef __attribute__((ext_vector_type(4))) float floatx4;   // MFMA C/D frag
typedef __attribute__((ext_vector_type(2))) long longx2;     // 16B = 2 MFMA operands
typedef unsigned int uint32;

#define BM 128
#define BN 128
#define BKB 64   // K-elements per B tile == bytes per row per tile (fp8)
#define NBUF 4

typedef const __attribute__((address_space(1))) unsigned int* as1_u32p;
typedef __attribute__((address_space(3))) unsigned int* as3_u32p;

__device__ __forceinline__ void load_lds16(const void* g, void* l) {
    // each lane writes 16B at (wave-uniform l) + lane*16
    __builtin_amdgcn_global_load_lds((as1_u32p)g, (as3_u32p)l, 16, 0, 0);
}

// grid-wide barrier, NO cache maintenance. __syncthreads drains each wave's
// vmcnt (compiler emits s_waitcnt vmcnt(0) before s_barrier), so all prior
// stores/atomics are committed; data flows through the coherent point.
__device__ __forceinline__ void gbar(uint32* c) {
    __syncthreads();
    if (threadIdx.x == 0) {
        atomicAdd(c, 1u);
        while (__hip_atomic_load(c, __ATOMIC_RELAXED, __HIP_MEMORY_SCOPE_AGENT) < GRID)
            __builtin_amdgcn_s_sleep(8);
    }
    __syncthreads();
}

// ---- gemm phase body (R9 core): A in regs, B 4-ring LDS, 1 barrier/iter.
// Wave w covers rows [w*16,+16); full 128-col tile; 8 b128 B-reads/k-chunk.
// EPI==0: S[row] += sum_col exp(C*invT); EPI==1: lsum over -log(pe/(pe+S)+eps).
template <int EPI, int TN>
__device__ __forceinline__ void gemm_body(const fp8_t* __restrict__ A,
                                          const fp8_t* __restrict__ Bm,
                                          float* __restrict__ S,
                                          float* __restrict__ loss_sum,
                                          int m0, int nt0, int tid,
                                          fp8_t (*Bl)[BN * BKB], float* redsc) {
    const int lane = tid & 63;
    const int w    = tid >> 6;          // 0..7 -> rows [w*16, w*16+16)
    const int lr   = lane & 15;
    const int q    = lane >> 4;

    // A fragments: lane holds true bytes [kt*64+q*16,+16) of row m0+w*16+lr
    // (matches B's granule mapping -> per-(q,half) true-k identical -> exact).
    longx2 af[8];
    {
        const fp8_t* arow = A + (size_t)(m0 + w * 16 + lr) * D_DIM + q * 16;
#pragma unroll
        for (int kt = 0; kt < 8; ++kt)
            af[kt] = *reinterpret_cast<const longx2*>(arow + kt * 64);
    }

    // B staging (measured-zero-conflict scheme, stride 64):
    // LDS[r*64 + s*16] holds true granule s^((r>>1)&3) of row r.
    const int sr = lane >> 2;
    const int sg = (lane & 3) ^ ((lane >> 3) & 3);
    const fp8_t* bbase = Bm + (size_t)(nt0 * BN + w * 16 + sr) * D_DIM + sg * 16;
    const int goff = (q ^ ((lr >> 1) & 3)) << 4;

    auto stage = [&](int tt) {
        load_lds16(bbase + (size_t)(tt >> 3) * (size_t)(BN * D_DIM)
                         + (size_t)((tt & 7) * BKB),
                   &Bl[tt & 3][w * 16 * BKB]);
    };

    float vac[4];
    float Sv[4];
    float lsum = 0.f;
    if (EPI == 0) {
#pragma unroll
        for (int reg = 0; reg < 4; ++reg) vac[reg] = 0.f;
    } else {
        // S was produced by device-scope atomics; read via coherent-point loads
#pragma unroll
        for (int reg = 0; reg < 4; ++reg)
            Sv[reg] = __hip_atomic_load(&S[m0 + w * 16 + q * 4 + reg],
                                        __ATOMIC_RELAXED, __HIP_MEMORY_SCOPE_AGENT);
    }

    stage(0);
    stage(1);

    for (int j = 0; j < TN; ++j) {
        floatx4 acc[8];
#pragma unroll
        for (int c = 0; c < 8; ++c) acc[c] = (floatx4){0.f, 0.f, 0.f, 0.f};

#pragma unroll
        for (int kt = 0; kt < 8; ++kt) {
            if (kt < 6 || j < TN - 1) {
                const int tt = j * 8 + kt + 2;
                stage(tt);   // ring dist 2, depth 4
                asm volatile("s_waitcnt vmcnt(2)" ::: "memory");
            } else if (kt == 6) {
                asm volatile("s_waitcnt vmcnt(1)" ::: "memory");
            } else {
                asm volatile("s_waitcnt vmcnt(0)" ::: "memory");
            }
            __builtin_amdgcn_sched_barrier(0);
            __builtin_amdgcn_s_barrier();   // only barrier: tile resident
            __builtin_amdgcn_sched_barrier(0);

            const fp8_t* bl = &Bl[(j * 8 + kt) & 3][0];
            __builtin_amdgcn_s_setprio(1);
#pragma unroll
            for (int ct = 0; ct < 8; ++ct) {
                const int r = ct * 16 + lr;
                longx2 b = *reinterpret_cast<const longx2*>(&bl[r * BKB + goff]);
                acc[ct] = __builtin_amdgcn_mfma_f32_16x16x32_fp8_fp8(
                    af[kt].x, b.x, acc[ct], 0, 0, 0);
                acc[ct] = __builtin_amdgcn_mfma_f32_16x16x32_fp8_fp8(
                    af[kt].y, b.y, acc[ct], 0, 0, 0);
            }
            __builtin_amdgcn_s_setprio(0);
            __builtin_amdgcn_sched_barrier(0);
        }

        // per-n-tile epilogue, register-only (vmcnt counts stay exact).
        // C/D layout: col = lane&15, row = (lane>>4)*4 + reg
        if (EPI == 0) {
#pragma unroll
            for (int reg = 0; reg < 4; ++reg) {
                float v = 0.f;
#pragma unroll
                for (int ct = 0; ct < 8; ++ct) v += __expf(acc[ct][reg] * INV_T);
                vac[reg] += v;
            }
        } else {
#pragma unroll
            for (int reg = 0; reg < 4; ++reg) {
                float s = Sv[reg];
#pragma unroll
                for (int ct = 0; ct < 8; ++ct) {
                    float pe = __expf(acc[ct][reg] * INV_T);
                    lsum -= __logf(pe / (pe + s) + EPS_L);
                }
            }
        }
    }

    if (EPI == 0) {
#pragma unroll
        for (int reg = 0; reg < 4; ++reg) {
            float v = vac[reg];
            v += __shfl_xor(v, 1);
            v += __shfl_xor(v, 2);
            v += __shfl_xor(v, 4);
            v += __shfl_xor(v, 8);
            if (lr == 0) atomicAdd(&S[m0 + w * 16 + q * 4 + reg], v);
        }
    } else {
#pragma unroll
        for (int off = 1; off < 64; off <<= 1) lsum += __shfl_xor(lsum, off);
        __syncthreads();
        if (lane == 0) redsc[w] = lsum;
        __syncthreads();
        if (tid == 0) {
            float s = 0.f;
#pragma unroll
            for (int i = 0; i < 8; ++i) s += redsc[i];
            atomicAdd(loss_sum, s);
        }
    }
}

// ================= fully fused kernel: 512 blocks x 512 threads =================
__global__ __launch_bounds__(512, 4) void fused_all(
        const float* __restrict__ anc, const float* __restrict__ pos,
        const float* __restrict__ neg,
        fp8_t* __restrict__ a8, fp8_t* __restrict__ p8, fp8_t* __restrict__ n8,
        float* __restrict__ S, float* __restrict__ csA, float* __restrict__ csP,
        float* __restrict__ csN, float* __restrict__ lsum,
        uint32* __restrict__ cnt, float* __restrict__ out) {
    __shared__ fp8_t Bl[NBUF][BN * BKB];   // 32 KB gemm ring (phase-0 overlay)
    __shared__ float redsc[32];
    __shared__ int lastf;

    const int b    = blockIdx.x;
    const int tid  = threadIdx.x;
    const int lane = tid & 63;
    const int w    = tid >> 6;

    // ---------------- phase 0: L2-normalize -> fp8, colsums ----------------
    // Perfectly balanced: wave wv handles rows wv + k*4096, k=0..5
    // (k=0 -> anc, k=1 -> pos, k=2..5 -> neg). 6 rows/wave everywhere.
    {
        float* fsh = reinterpret_cast<float*>(&Bl[0][0]);  // 1536 floats
        fsh[tid] = 0.f; fsh[tid + 512] = 0.f; fsh[tid + 1024] = 0.f;

        const int wv = b * 8 + w;
        float c0[3][4], c1[3][4];
#pragma unroll
        for (int s = 0; s < 3; ++s)
#pragma unroll
            for (int j = 0; j < 4; ++j) { c0[s][j] = 0.f; c1[s][j] = 0.f; }

#pragma unroll
        for (int k = 0; k < 6; ++k) {
            const int seg   = (k == 0) ? 0 : (k == 1) ? 1 : 2;
            const float* in = (k == 0) ? anc : (k == 1) ? pos : neg;
            fp8_t* op8      = (k == 0) ? a8 : (k == 1) ? p8 : n8;
            const int r     = (k <= 1) ? wv : (wv + (k - 2) * B_ROWS);

            const float4* rp = reinterpret_cast<const float4*>(in + (size_t)r * D_DIM);
            float4 v0 = rp[lane];
            float4 v1 = rp[lane + 64];
            float ss = v0.x*v0.x + v0.y*v0.y + v0.z*v0.z + v0.w*v0.w
                     + v1.x*v1.x + v1.y*v1.y + v1.z*v1.z + v1.w*v1.w;
#pragma unroll
            for (int off = 1; off < 64; off <<= 1) ss += __shfl_xor(ss, off);
            float inv = 1.0f / fmaxf(sqrtf(ss), 1e-12f);
            float f0x = v0.x*inv, f0y = v0.y*inv, f0z = v0.z*inv, f0w = v0.w*inv;
            float f1x = v1.x*inv, f1y = v1.y*inv, f1z = v1.z*inv, f1w = v1.w*inv;
            c0[seg][0] += f0x; c0[seg][1] += f0y; c0[seg][2] += f0z; c0[seg][3] += f0w;
            c1[seg][0] += f1x; c1[seg][1] += f1y; c1[seg][2] += f1z; c1[seg][3] += f1w;
            int pk0 = __builtin_amdgcn_cvt_pk_fp8_f32(f0x, f0y, 0, 0);
            pk0     = __builtin_amdgcn_cvt_pk_fp8_f32(f0z, f0w, pk0, 1);
            int pk1 = __builtin_amdgcn_cvt_pk_fp8_f32(f1x, f1y, 0, 0);
            pk1     = __builtin_amdgcn_cvt_pk_fp8_f32(f1z, f1w, pk1, 1);
            // publish via coherent-point stores (bypass non-coherent L2):
            // readers on other XCDs never cached these lines -> fresh reads.
            uint32* op = reinterpret_cast<uint32*>(op8 + (size_t)r * D_DIM);
            __hip_atomic_store(op + lane, (uint32)pk0,
                               __ATOMIC_RELAXED, __HIP_MEMORY_SCOPE_AGENT);
            __hip_atomic_store(op + lane + 64, (uint32)pk1,
                               __ATOMIC_RELAXED, __HIP_MEMORY_SCOPE_AGENT);
        }

        __syncthreads();   // fsh zeroing complete
#pragma unroll
        for (int s = 0; s < 3; ++s)
#pragma unroll
            for (int j = 0; j < 4; ++j) {
                atomicAdd(&fsh[s * 512 + lane * 4 + j], c0[s][j]);
                atomicAdd(&fsh[s * 512 + 256 + lane * 4 + j], c1[s][j]);
            }
        __syncthreads();
        atomicAdd(&csA[(size_t)tid * CS_STRIDE], fsh[tid]);
        atomicAdd(&csP[(size_t)tid * CS_STRIDE], fsh[512 + tid]);
        atomicAdd(&csN[(size_t)tid * CS_STRIDE], fsh[1024 + tid]);
    }

    gbar(&cnt[0]);   // fp8 + colsums committed at coherent point

    // ---------------- phase 1: neg GEMM (S exp-sums) ----------------
    gemm_body<0, 8>(a8, n8, S, nullptr, (b >> 4) * BM, (b & 15) * 8, tid, Bl, redsc);

    gbar(&cnt[1]);   // S complete

    // ---------------- phase 2: pos GEMM (loss) ----------------
    gemm_body<1, 2>(a8, p8, S, lsum, (b >> 4) * BM, (b & 15) * 2, tid, Bl, redsc);

    // ---------------- arrive; last block finalizes ----------------
    __syncthreads();
    if (tid == 0) {
        uint32 p = atomicAdd(&cnt[2], 1u);
        lastf = (p == GRID - 1);
    }
    __syncthreads();
    if (lastf) {
        float av = __hip_atomic_load(&csA[(size_t)tid * CS_STRIDE],
                                     __ATOMIC_RELAXED, __HIP_MEMORY_SCOPE_AGENT);
        float pv = __hip_atomic_load(&csP[(size_t)tid * CS_STRIDE],
                                     __ATOMIC_RELAXED, __HIP_MEMORY_SCOPE_AGENT);
        float nv = __hip_atomic_load(&csN[(size_t)tid * CS_STRIDE],
                                     __ATOMIC_RELAXED, __HIP_MEMORY_SCOPE_AGENT);
        float dp = av * pv;
        float dn = av * nv;
#pragma unroll
        for (int off = 1; off < 64; off <<= 1) {
            dp += __shfl_xor(dp, off);
            dn += __shfl_xor(dn, off);
        }
        __syncthreads();
        if (lane == 0) { redsc[w] = dp; redsc[8 + w] = dn; }
        __syncthreads();
        if (tid == 0) {
            float sdp = 0.f, sdn = 0.f;
#pragma unroll
            for (int i = 0; i < 8; ++i) { sdp += redsc[i]; sdn += redsc[8 + i]; }
            float ls = __hip_atomic_load(lsum, __ATOMIC_RELAXED,
                                         __HIP_MEMORY_SCOPE_AGENT);
            float mean_pos = sdp * INV_T / ((float)B_ROWS * (float)P_ROWS);
            float mean_neg = sdn * INV_T / ((float)B_ROWS * (float)N_ROWS);
            out[0] = ls / ((float)B_ROWS * (float)P_ROWS);
            out[1] = mean_pos;
            out[2] = mean_neg;
            out[3] = mean_pos - mean_neg;
        }
    }
}

extern "C" void kernel_launch(void* const* d_in, const int* in_sizes, int n_in,
                              void* d_out, int out_size, void* d_ws, size_t ws_size,
                              hipStream_t stream) {
    const float* anc = (const float*)d_in[0];
    const float* pos = (const float*)d_in[1];
    const float* neg = (const float*)d_in[2];
    float* out = (float*)d_out;

    fp8_t* a8 = (fp8_t*)d_ws;
    fp8_t* p8 = a8 + (size_t)B_ROWS * D_DIM;
    fp8_t* n8 = p8 + (size_t)P_ROWS * D_DIM;
    float* fsec = (float*)(n8 + (size_t)N_ROWS * D_DIM);  // 12MB offset, 64B-aligned
    float* S    = fsec;                        // 4096
    float* csA  = S + B_ROWS;                  // 512*16
    float* csP  = csA + D_DIM * CS_STRIDE;     // 512*16
    float* csN  = csP + D_DIM * CS_STRIDE;     // 512*16
    float* lsum = csN + D_DIM * CS_STRIDE;     // 1 (+3 pad)
    uint32* cnt = (uint32*)(lsum + 4);         // 3 barrier/arrive counters

    // ws is re-poisoned 0xAA before every launch -> zero accumulators + counters
    (void)hipMemsetAsync(fsec, 0, (B_ROWS + 3 * D_DIM * CS_STRIDE + 8) * sizeof(float), stream);

    fused_all<<<GRID, 512, 0, stream>>>(anc, pos, neg, a8, p8, n8,
                                        S, csA, csP, csN, lsum, cnt, out);
}

// Round 11
// 228.981 us; speedup vs baseline: 1.0928x; 1.0928x over previous
//
#include <hip/hip_runtime.h>
#include <hip/hip_bf16.h>

// InfoNCE: a[4096,512], p[4096,512], n[16384,512] f32 -> 4 f32 scalars.
// R15: R9 (best measured, 191us total / gemm0 52.8us) with ONE change:
//     4 blocks/CU instead of 2. R14 post-mortem: fence-free fusion still
//     ~100us slower than split phase-sum (MfmaUtil 18%) -> fusion abandoned;
//     node-count theory dead (R9 5-node 191 < R12 4-node 205). gemm0's
//     53-56us plateau survived LDS-volume (R12) and barrier-count (R13)
//     changes -> residual is the per-iteration barrier wait, absorbable only
//     by MORE INDEPENDENT BLOCK CONTEXTS per CU (m114 mechanism). R9 uses
//     48 VGPR -> fits 8 waves/SIMD (cap 64). launch_bounds(512,8) + grid
//     1024 (TN=4 for gemm0, TN=1 for gemm1) -> 4 co-resident 512-thr blocks
//     per CU (LDS 4x32KB=128KB <= 160KB). When one block stalls at its
//     s_barrier, three others issue MFMAs (previously one).
// ws layout: a8(2MB) p8(2MB) n8(8MB) | S[4096] csA[8192] csP[8192] csN[8192]
//            lsum[1] pad[3] cnt[4]

#define D_DIM 512
#define B_ROWS 4096
#define P_ROWS 4096
#define N_ROWS 16384
#define INV_T 14.285714285714286f
#define EPS_L 1e-8f
#define CS_STRIDE 16  // colsum accumulators spread 64B apart -> atomics hit distinct lines

typedef unsigned char fp8_t;
typedef __attribute__((ext_vector_type(4))) float floatx4;   // MFMA C/D frag
typedef __attribute__((ext_vector_type(2))) long longx2;     // 16B = 2 MFMA operands
typedef unsigned int uint32;

// ---- fused: L2-normalize rows -> fp8 e4m3, and accumulate fp32 column sums ----
// grid = 1024 blocks x 256 thr. Segments: b<256 -> A, b<512 -> P, else -> N.
__global__ __launch_bounds__(256) void norm_colsum(
        const float* __restrict__ a, const float* __restrict__ p, const float* __restrict__ n,
        fp8_t* __restrict__ a8, fp8_t* __restrict__ p8, fp8_t* __restrict__ n8,
        float* __restrict__ csA, float* __restrict__ csP, float* __restrict__ csN) {
    const float* in; fp8_t* outp; float* cs; int rows, nb, bseg;
    int b = blockIdx.x;
    if (b < 256)      { in = a; outp = a8; cs = csA; rows = B_ROWS; nb = 256; bseg = b; }
    else if (b < 512) { in = p; outp = p8; cs = csP; rows = P_ROWS; nb = 256; bseg = b - 256; }
    else              { in = n; outp = n8; cs = csN; rows = N_ROWS; nb = 512; bseg = b - 512; }

    const int wave = threadIdx.x >> 6;
    const int lane = threadIdx.x & 63;

    float cs0[4] = {0.f, 0.f, 0.f, 0.f};
    float cs1[4] = {0.f, 0.f, 0.f, 0.f};

    for (int chunk = bseg; chunk < (rows >> 2); chunk += nb) {
        int r = chunk * 4 + wave;
        const float4* rp = reinterpret_cast<const float4*>(in + (size_t)r * D_DIM);
        float4 v0 = rp[lane];
        float4 v1 = rp[lane + 64];
        float ss = v0.x*v0.x + v0.y*v0.y + v0.z*v0.z + v0.w*v0.w
                 + v1.x*v1.x + v1.y*v1.y + v1.z*v1.z + v1.w*v1.w;
#pragma unroll
        for (int off = 1; off < 64; off <<= 1) ss += __shfl_xor(ss, off);
        float inv = 1.0f / fmaxf(sqrtf(ss), 1e-12f);
        float f0x = v0.x*inv, f0y = v0.y*inv, f0z = v0.z*inv, f0w = v0.w*inv;
        float f1x = v1.x*inv, f1y = v1.y*inv, f1z = v1.z*inv, f1w = v1.w*inv;
        cs0[0] += f0x; cs0[1] += f0y; cs0[2] += f0z; cs0[3] += f0w;
        cs1[0] += f1x; cs1[1] += f1y; cs1[2] += f1z; cs1[3] += f1w;
        // pack 4 floats -> 4 fp8 e4m3 bytes (RNE hw cvt)
        int pk0 = __builtin_amdgcn_cvt_pk_fp8_f32(f0x, f0y, 0, 0);
        pk0     = __builtin_amdgcn_cvt_pk_fp8_f32(f0z, f0w, pk0, 1);
        int pk1 = __builtin_amdgcn_cvt_pk_fp8_f32(f1x, f1y, 0, 0);
        pk1     = __builtin_amdgcn_cvt_pk_fp8_f32(f1z, f1w, pk1, 1);
        uint32* op = reinterpret_cast<uint32*>(outp + (size_t)r * D_DIM);
        op[lane]      = (uint32)pk0;   // bytes 4*lane .. 4*lane+3
        op[lane + 64] = (uint32)pk1;   // bytes 256+4*lane ..
    }

    // block-level colsum reduce: LDS atomics (4-way max contention), then one
    // global atomic per column per block, spread across 64B lines.
    __shared__ float csh[D_DIM];
    if (threadIdx.x < 256) { csh[threadIdx.x] = 0.f; csh[threadIdx.x + 256] = 0.f; }
    __syncthreads();
#pragma unroll
    for (int j = 0; j < 4; ++j) {
        atomicAdd(&csh[lane * 4 + j], cs0[j]);
        atomicAdd(&csh[256 + lane * 4 + j], cs1[j]);
    }
    __syncthreads();
    if (threadIdx.x < 256) {
        atomicAdd(&cs[(size_t)threadIdx.x * CS_STRIDE], csh[threadIdx.x]);
        atomicAdd(&cs[(size_t)(threadIdx.x + 256) * CS_STRIDE], csh[threadIdx.x + 256]);
    }
}

// ------------- fp8 MFMA GEMM: A in regs, B 4-ring LDS, 1 barrier/iter -------------
#define BM 128
#define BN 128
#define BKB 64   // K-elements per B tile == bytes per row per tile (fp8)
#define NBUF 4

typedef const __attribute__((address_space(1))) unsigned int* as1_u32p;
typedef __attribute__((address_space(3))) unsigned int* as3_u32p;

__device__ __forceinline__ void load_lds16(const void* g, void* l) {
    // each lane writes 16B at (wave-uniform l) + lane*16
    __builtin_amdgcn_global_load_lds((as1_u32p)g, (as3_u32p)l, 16, 0, 0);
}

// stage linear tile tt (n-tile tt>>3, k-chunk tt&7) into ring buf tt&3; this
// wave covers rows [w*16, w*16+16) of the BN=128 tile (64 lanes x 16B = 1KB).
#define STAGE_B(tt) load_lds16(                                                   \
        bbase + (size_t)((tt) >> 3) * (size_t)(BN * D_DIM) + (size_t)(((tt) & 7) * BKB), \
        &Bl[(tt) & 3][w * 16 * BKB])

// EPI==0: C = A@Bm^T, S[row] += sum_col exp(C*invT)           (neg pass)
// EPI==1: loss_sum += sum(-log(exp(C*invT)/(exp+S[row])+eps)) (pos pass)
// Block: 512 thr = 8 waves x 16 rows; sweeps TN n-tiles with A in registers.
// launch_bounds(512, 8): 8 waves/SIMD -> 4 co-resident blocks/CU (VGPR cap 64;
// R9 measured 48). Cross-block overlap absorbs the per-iteration barrier wait.
template <int EPI, int TN>
__global__ __launch_bounds__(512, 8) void gemm_epi(const fp8_t* __restrict__ A,
                                                   const fp8_t* __restrict__ Bm,
                                                   float* __restrict__ S,
                                                   float* __restrict__ loss_sum) {
    __shared__ fp8_t Bl[NBUF][BN * BKB];   // 4 x 8 KB ring

    const int tid  = threadIdx.x;
    const int lane = tid & 63;
    const int w    = tid >> 6;          // wave 0..7 -> rows [w*16, w*16+16)
    const int m0   = blockIdx.y * BM;
    const int nt0  = blockIdx.x * TN;   // first n-tile index
    const int lr   = lane & 15;         // A/B input row within 16-tile (= out col)
    const int q    = lane >> 4;         // quad 0..3

    // ---- A panel -> registers: lane holds true bytes [kt*64+q*16, +16) of
    // row m0+w*16+lr for kt=0..7 (32 VGPR). Matches B's granule mapping.
    longx2 af[8];
    {
        const fp8_t* arow = A + (size_t)(m0 + w * 16 + lr) * D_DIM + q * 16;
#pragma unroll
        for (int kt = 0; kt < 8; ++kt)
            af[kt] = *reinterpret_cast<const longx2*>(arow + kt * 64);
    }

    // ---- B staging constants (measured-zero-conflict scheme, stride 64):
    // LDS[r*64 + s*16] holds true granule s^((r>>1)&3) of row r.
    const int sr = lane >> 2;                        // row 0..15 within the 16-row slice
    const int sg = (lane & 3) ^ ((lane >> 3) & 3);   // inverse-swizzled source granule
    const fp8_t* bbase = Bm + (size_t)(nt0 * BN + w * 16 + sr) * D_DIM + sg * 16;
    // fragment read: lane wants true granule q of its row -> slot q^((r>>1)&3)
    const int goff = (q ^ ((lr >> 1) & 3)) << 4;

    float vac[4];   // EPI0: per-row exp-sum partials (rows q*4+reg), acc over n-tiles
    float Sv[4];    // EPI1: cached denominators
    float lsum = 0.f;
    if (EPI == 0) {
#pragma unroll
        for (int reg = 0; reg < 4; ++reg) vac[reg] = 0.f;
    } else {
#pragma unroll
        for (int reg = 0; reg < 4; ++reg)
            Sv[reg] = S[m0 + w * 16 + q * 4 + reg];
    }

    // prologue: tiles 0 and 1 in flight (1 load each per wave)
    STAGE_B(0);
    STAGE_B(1);

    for (int j = 0; j < TN; ++j) {
        floatx4 acc[8];
#pragma unroll
        for (int c = 0; c < 8; ++c) acc[c] = (floatx4){0.f, 0.f, 0.f, 0.f};

#pragma unroll
        for (int kt = 0; kt < 8; ++kt) {
            // prefetch tile T+2 into ring (kt+2)&3; its previous readers (tile
            // T-2) finished before barrier T-1, which we've already passed.
            if (kt < 6 || j < TN - 1) {
                const int tt = j * 8 + kt + 2;
                STAGE_B(tt);
                asm volatile("s_waitcnt vmcnt(2)" ::: "memory");  // tile T landed
            } else if (kt == 6) {
                asm volatile("s_waitcnt vmcnt(1)" ::: "memory");
            } else {
                asm volatile("s_waitcnt vmcnt(0)" ::: "memory");
            }
            __builtin_amdgcn_sched_barrier(0);
            __builtin_amdgcn_s_barrier();   // ONLY barrier: tile T resident for all
            __builtin_amdgcn_sched_barrier(0);

            const fp8_t* bl = &Bl[kt & 3][0];
            __builtin_amdgcn_s_setprio(1);
#pragma unroll
            for (int ct = 0; ct < 8; ++ct) {
                const int r = ct * 16 + lr;
                longx2 b = *reinterpret_cast<const longx2*>(&bl[r * BKB + goff]);
                // true k [kt*64+16q, +8) (.x) and +8 (.y) on BOTH sides -> exact
                acc[ct] = __builtin_amdgcn_mfma_f32_16x16x32_fp8_fp8(
                    af[kt].x, b.x, acc[ct], 0, 0, 0);
                acc[ct] = __builtin_amdgcn_mfma_f32_16x16x32_fp8_fp8(
                    af[kt].y, b.y, acc[ct], 0, 0, 0);
            }
            __builtin_amdgcn_s_setprio(0);
            __builtin_amdgcn_sched_barrier(0);
        }

        // ---- per-n-tile epilogue: register-only (vmcnt counts stay exact) ----
        // C/D layout: col = lane&15, row = (lane>>4)*4 + reg
        if (EPI == 0) {
#pragma unroll
            for (int reg = 0; reg < 4; ++reg) {
                float v = 0.f;
#pragma unroll
                for (int ct = 0; ct < 8; ++ct) v += __expf(acc[ct][reg] * INV_T);
                vac[reg] += v;
            }
        } else {
#pragma unroll
            for (int reg = 0; reg < 4; ++reg) {
                float s = Sv[reg];
#pragma unroll
                for (int ct = 0; ct < 8; ++ct) {
                    float pe = __expf(acc[ct][reg] * INV_T);
                    lsum -= __logf(pe / (pe + s) + EPS_L);
                }
            }
        }
    }

    // ---- final reductions + atomics (once per block) ----
    if (EPI == 0) {
#pragma unroll
        for (int reg = 0; reg < 4; ++reg) {
            float v = vac[reg];
            v += __shfl_xor(v, 1);
            v += __shfl_xor(v, 2);
            v += __shfl_xor(v, 4);
            v += __shfl_xor(v, 8);
            if (lr == 0) atomicAdd(&S[m0 + w * 16 + q * 4 + reg], v);
        }
    } else {
#pragma unroll
        for (int off = 1; off < 64; off <<= 1) lsum += __shfl_xor(lsum, off);
        // 8 waves -> 1 global atomic per block via LDS scratch (ring is dead)
        __syncthreads();
        float* red = reinterpret_cast<float*>(&Bl[0][0]);
        if (lane == 0) red[w] = lsum;
        __syncthreads();
        if (tid == 0) {
            float s = 0.f;
#pragma unroll
            for (int i = 0; i < 8; ++i) s += red[i];
            atomicAdd(loss_sum, s);
        }
    }
}

// ---- finalize: dot the (strided) column sums, emit the 4 scalars ----
__global__ void finalize_k(const float* __restrict__ csA, const float* __restrict__ csP,
                           const float* __restrict__ csN, const float* __restrict__ lsum,
                           float* __restrict__ out) {
    int tid = threadIdx.x;  // 512
    float av = csA[(size_t)tid * CS_STRIDE];
    float dp = av * csP[(size_t)tid * CS_STRIDE];
    float dn = av * csN[(size_t)tid * CS_STRIDE];
#pragma unroll
    for (int off = 1; off < 64; off <<= 1) {
        dp += __shfl_xor(dp, off);
        dn += __shfl_xor(dn, off);
    }
    __shared__ float red[16];
    int wid = tid >> 6, lane = tid & 63;
    if (lane == 0) { red[wid] = dp; red[8 + wid] = dn; }
    __syncthreads();
    if (tid == 0) {
        float sdp = 0.f, sdn = 0.f;
#pragma unroll
        for (int i = 0; i < 8; ++i) { sdp += red[i]; sdn += red[8 + i]; }
        float mean_pos = sdp * INV_T / ((float)B_ROWS * (float)P_ROWS);
        float mean_neg = sdn * INV_T / ((float)B_ROWS * (float)N_ROWS);
        out[0] = lsum[0] / ((float)B_ROWS * (float)P_ROWS);
        out[1] = mean_pos;
        out[2] = mean_neg;
        out[3] = mean_pos - mean_neg;
    }
}

extern "C" void kernel_launch(void* const* d_in, const int* in_sizes, int n_in,
                              void* d_out, int out_size, void* d_ws, size_t ws_size,
                              hipStream_t stream) {
    const float* anc = (const float*)d_in[0];
    const float* pos = (const float*)d_in[1];
    const float* neg = (const float*)d_in[2];
    float* out = (float*)d_out;

    fp8_t* a8 = (fp8_t*)d_ws;
    fp8_t* p8 = a8 + (size_t)B_ROWS * D_DIM;
    fp8_t* n8 = p8 + (size_t)P_ROWS * D_DIM;
    float* fsec = (float*)(n8 + (size_t)N_ROWS * D_DIM);  // 12MB offset, 64B-aligned
    float* S    = fsec;                        // 4096
    float* csA  = S + B_ROWS;                  // 512*16
    float* csP  = csA + D_DIM * CS_STRIDE;     // 512*16
    float* csN  = csP + D_DIM * CS_STRIDE;     // 512*16
    float* lsum = csN + D_DIM * CS_STRIDE;     // 1

    // ws is re-poisoned 0xAA before every launch -> zero all accumulators
    (void)hipMemsetAsync(fsec, 0, (B_ROWS + 3 * D_DIM * CS_STRIDE + 1) * sizeof(float), stream);

    norm_colsum<<<1024, 256, 0, stream>>>(anc, pos, neg, a8, p8, n8, csA, csP, csN);

    // 1024 blocks each -> 4 co-resident 512-thr blocks/CU (8 waves/SIMD).
    gemm_epi<0, 4><<<dim3((N_ROWS / BN) / 4, B_ROWS / BM), 512, 0, stream>>>(a8, n8, S, nullptr);
    gemm_epi<1, 1><<<dim3((P_ROWS / BN) / 1, B_ROWS / BM), 512, 0, stream>>>(a8, p8, S, lsum);

    finalize_k<<<1, 512, 0, stream>>>(csA, csP, csN, lsum, out);
}

// Round 12
// 203.333 us; speedup vs baseline: 1.2307x; 1.1261x over previous
//
#include <hip/hip_runtime.h>
#include <hip/hip_bf16.h>

// InfoNCE: a[4096,512], p[4096,512], n[16384,512] f32 -> 4 f32 scalars.
// R16: R9 core + 3 blocks/CU via launch_bounds(512,6) + finalize folded into
//     gemm1 (R12-proven tail). R15 post-mortem: (512,8) capped unified VGPR
//     at 64 < 64 data regs (af 32 + acc 32) -> catastrophic spill (FETCH
//     113MB, WRITE 90MB scratch, gemm0 79.9us) BUT occupancy rose 33->66%:
//     mechanism valid, budget wasn't. R9 footprint ~80 unified (48 arch +
//     32 AGPR); 6-wave cap = 85 -> fits with ~5 spare. Grid TN=4 (1024
//     blocks) so the 3rd block slot per CU is populated (768 resident).
//     gemm1 keeps (512,4) known-good. Nodes 5 -> 4.
// ws layout: a8(2MB) p8(2MB) n8(8MB) | S[4096] csA[8192] csP[8192] csN[8192]
//            lsum[1] pad[3] cnt[4]

#define D_DIM 512
#define B_ROWS 4096
#define P_ROWS 4096
#define N_ROWS 16384
#define INV_T 14.285714285714286f
#define EPS_L 1e-8f
#define CS_STRIDE 16
#define GRID_POS 512   // gemm_pos_fin block count (arrive counter target)

typedef unsigned char fp8_t;
typedef __attribute__((ext_vector_type(4))) float floatx4;   // MFMA C/D frag
typedef __attribute__((ext_vector_type(2))) long longx2;     // 16B = 2 MFMA operands
typedef unsigned int uint32;

// ---- fused: L2-normalize rows -> fp8 e4m3, and accumulate fp32 column sums ----
// grid = 1024 blocks x 256 thr. Segments: b<256 -> A, b<512 -> P, else -> N.
__global__ __launch_bounds__(256) void norm_colsum(
        const float* __restrict__ a, const float* __restrict__ p, const float* __restrict__ n,
        fp8_t* __restrict__ a8, fp8_t* __restrict__ p8, fp8_t* __restrict__ n8,
        float* __restrict__ csA, float* __restrict__ csP, float* __restrict__ csN) {
    const float* in; fp8_t* outp; float* cs; int rows, nb, bseg;
    int b = blockIdx.x;
    if (b < 256)      { in = a; outp = a8; cs = csA; rows = B_ROWS; nb = 256; bseg = b; }
    else if (b < 512) { in = p; outp = p8; cs = csP; rows = P_ROWS; nb = 256; bseg = b - 256; }
    else              { in = n; outp = n8; cs = csN; rows = N_ROWS; nb = 512; bseg = b - 512; }

    const int wave = threadIdx.x >> 6;
    const int lane = threadIdx.x & 63;

    float cs0[4] = {0.f, 0.f, 0.f, 0.f};
    float cs1[4] = {0.f, 0.f, 0.f, 0.f};

    for (int chunk = bseg; chunk < (rows >> 2); chunk += nb) {
        int r = chunk * 4 + wave;
        const float4* rp = reinterpret_cast<const float4*>(in + (size_t)r * D_DIM);
        float4 v0 = rp[lane];
        float4 v1 = rp[lane + 64];
        float ss = v0.x*v0.x + v0.y*v0.y + v0.z*v0.z + v0.w*v0.w
                 + v1.x*v1.x + v1.y*v1.y + v1.z*v1.z + v1.w*v1.w;
#pragma unroll
        for (int off = 1; off < 64; off <<= 1) ss += __shfl_xor(ss, off);
        float inv = 1.0f / fmaxf(sqrtf(ss), 1e-12f);
        float f0x = v0.x*inv, f0y = v0.y*inv, f0z = v0.z*inv, f0w = v0.w*inv;
        float f1x = v1.x*inv, f1y = v1.y*inv, f1z = v1.z*inv, f1w = v1.w*inv;
        cs0[0] += f0x; cs0[1] += f0y; cs0[2] += f0z; cs0[3] += f0w;
        cs1[0] += f1x; cs1[1] += f1y; cs1[2] += f1z; cs1[3] += f1w;
        // pack 4 floats -> 4 fp8 e4m3 bytes (RNE hw cvt)
        int pk0 = __builtin_amdgcn_cvt_pk_fp8_f32(f0x, f0y, 0, 0);
        pk0     = __builtin_amdgcn_cvt_pk_fp8_f32(f0z, f0w, pk0, 1);
        int pk1 = __builtin_amdgcn_cvt_pk_fp8_f32(f1x, f1y, 0, 0);
        pk1     = __builtin_amdgcn_cvt_pk_fp8_f32(f1z, f1w, pk1, 1);
        uint32* op = reinterpret_cast<uint32*>(outp + (size_t)r * D_DIM);
        op[lane]      = (uint32)pk0;   // bytes 4*lane .. 4*lane+3
        op[lane + 64] = (uint32)pk1;   // bytes 256+4*lane ..
    }

    // block-level colsum reduce: LDS atomics (4-way max contention), then one
    // global atomic per column per block, spread across 64B lines.
    __shared__ float csh[D_DIM];
    if (threadIdx.x < 256) { csh[threadIdx.x] = 0.f; csh[threadIdx.x + 256] = 0.f; }
    __syncthreads();
#pragma unroll
    for (int j = 0; j < 4; ++j) {
        atomicAdd(&csh[lane * 4 + j], cs0[j]);
        atomicAdd(&csh[256 + lane * 4 + j], cs1[j]);
    }
    __syncthreads();
    if (threadIdx.x < 256) {
        atomicAdd(&cs[(size_t)threadIdx.x * CS_STRIDE], csh[threadIdx.x]);
        atomicAdd(&cs[(size_t)(threadIdx.x + 256) * CS_STRIDE], csh[threadIdx.x + 256]);
    }
}

// ------------- fp8 MFMA GEMM: A in regs, B 4-ring LDS, 1 barrier/iter -------------
#define BM 128
#define BN 128
#define BKB 64   // K-elements per B tile == bytes per row per tile (fp8)
#define NBUF 4

typedef const __attribute__((address_space(1))) unsigned int* as1_u32p;
typedef __attribute__((address_space(3))) unsigned int* as3_u32p;

__device__ __forceinline__ void load_lds16(const void* g, void* l) {
    // each lane writes 16B at (wave-uniform l) + lane*16
    __builtin_amdgcn_global_load_lds((as1_u32p)g, (as3_u32p)l, 16, 0, 0);
}

// ---- gemm phase body (R9 core verbatim): wave w covers rows [w*16,+16);
// full 128-col B tile; 8 b128 B-reads + 16 MFMA per k-chunk; ring dist 2.
// EPI==0: S[row] += sum_col exp(C*invT); EPI==1: lsum over -log(pe/(pe+S)+eps).
template <int EPI, int TN>
__device__ __forceinline__ void gemm_body(const fp8_t* __restrict__ A,
                                          const fp8_t* __restrict__ Bm,
                                          float* __restrict__ S,
                                          float* __restrict__ loss_sum,
                                          int m0, int nt0, int tid,
                                          fp8_t (*Bl)[BN * BKB]) {
    const int lane = tid & 63;
    const int w    = tid >> 6;          // 0..7 -> rows [w*16, w*16+16)
    const int lr   = lane & 15;
    const int q    = lane >> 4;

    // A fragments: lane holds true bytes [kt*64+q*16,+16) of row m0+w*16+lr
    // (matches B's granule mapping -> per-(q,half) true-k identical -> exact).
    longx2 af[8];
    {
        const fp8_t* arow = A + (size_t)(m0 + w * 16 + lr) * D_DIM + q * 16;
#pragma unroll
        for (int kt = 0; kt < 8; ++kt)
            af[kt] = *reinterpret_cast<const longx2*>(arow + kt * 64);
    }

    // B staging (measured-zero-conflict scheme, stride 64):
    // LDS[r*64 + s*16] holds true granule s^((r>>1)&3) of row r.
    const int sr = lane >> 2;
    const int sg = (lane & 3) ^ ((lane >> 3) & 3);
    const fp8_t* bbase = Bm + (size_t)(nt0 * BN + w * 16 + sr) * D_DIM + sg * 16;
    const int goff = (q ^ ((lr >> 1) & 3)) << 4;

    auto stage = [&](int tt) {
        load_lds16(bbase + (size_t)(tt >> 3) * (size_t)(BN * D_DIM)
                         + (size_t)((tt & 7) * BKB),
                   &Bl[tt & 3][w * 16 * BKB]);
    };

    float vac[4];
    float Sv[4];
    float lsum = 0.f;
    if (EPI == 0) {
#pragma unroll
        for (int reg = 0; reg < 4; ++reg) vac[reg] = 0.f;
    } else {
#pragma unroll
        for (int reg = 0; reg < 4; ++reg)
            Sv[reg] = S[m0 + w * 16 + q * 4 + reg];
    }

    stage(0);
    stage(1);

    for (int j = 0; j < TN; ++j) {
        floatx4 acc[8];
#pragma unroll
        for (int c = 0; c < 8; ++c) acc[c] = (floatx4){0.f, 0.f, 0.f, 0.f};

#pragma unroll
        for (int kt = 0; kt < 8; ++kt) {
            if (kt < 6 || j < TN - 1) {
                const int tt = j * 8 + kt + 2;
                stage(tt);   // ring dist 2, depth 4: writers never collide
                asm volatile("s_waitcnt vmcnt(2)" ::: "memory");  // tile landed
            } else if (kt == 6) {
                asm volatile("s_waitcnt vmcnt(1)" ::: "memory");
            } else {
                asm volatile("s_waitcnt vmcnt(0)" ::: "memory");
            }
            __builtin_amdgcn_sched_barrier(0);
            __builtin_amdgcn_s_barrier();   // ONLY barrier: tile resident
            __builtin_amdgcn_sched_barrier(0);

            const fp8_t* bl = &Bl[kt & 3][0];
            __builtin_amdgcn_s_setprio(1);
#pragma unroll
            for (int ct = 0; ct < 8; ++ct) {
                const int r = ct * 16 + lr;
                longx2 b = *reinterpret_cast<const longx2*>(&bl[r * BKB + goff]);
                acc[ct] = __builtin_amdgcn_mfma_f32_16x16x32_fp8_fp8(
                    af[kt].x, b.x, acc[ct], 0, 0, 0);
                acc[ct] = __builtin_amdgcn_mfma_f32_16x16x32_fp8_fp8(
                    af[kt].y, b.y, acc[ct], 0, 0, 0);
            }
            __builtin_amdgcn_s_setprio(0);
            __builtin_amdgcn_sched_barrier(0);
        }

        // per-n-tile epilogue, register-only (vmcnt counts stay exact).
        // C/D layout: col = lane&15, row = (lane>>4)*4 + reg
        if (EPI == 0) {
#pragma unroll
            for (int reg = 0; reg < 4; ++reg) {
                float v = 0.f;
#pragma unroll
                for (int ct = 0; ct < 8; ++ct) v += __expf(acc[ct][reg] * INV_T);
                vac[reg] += v;
            }
        } else {
#pragma unroll
            for (int reg = 0; reg < 4; ++reg) {
                float s = Sv[reg];
#pragma unroll
                for (int ct = 0; ct < 8; ++ct) {
                    float pe = __expf(acc[ct][reg] * INV_T);
                    lsum -= __logf(pe / (pe + s) + EPS_L);
                }
            }
        }
    }

    if (EPI == 0) {
#pragma unroll
        for (int reg = 0; reg < 4; ++reg) {
            float v = vac[reg];
            v += __shfl_xor(v, 1);
            v += __shfl_xor(v, 2);
            v += __shfl_xor(v, 4);
            v += __shfl_xor(v, 8);
            if (lr == 0) atomicAdd(&S[m0 + w * 16 + q * 4 + reg], v);
        }
    } else {
#pragma unroll
        for (int off = 1; off < 64; off <<= 1) lsum += __shfl_xor(lsum, off);
        // 8 waves -> 1 global atomic per block via LDS scratch (ring is dead)
        __syncthreads();
        float* red = reinterpret_cast<float*>(&Bl[0][0]);
        if (lane == 0) red[w] = lsum;
        __syncthreads();
        if (tid == 0) {
            float s = 0.f;
#pragma unroll
            for (int i = 0; i < 8; ++i) s += red[i];
            atomicAdd(loss_sum, s);
        }
    }
}

// ---- gemm0: neg pass. (512,6): 6 waves/SIMD -> 3 blocks/CU, VGPR cap 85
// (kernel needs ~80 unified). Grid 1024 (TN=4) populates the 3rd slot.
__global__ __launch_bounds__(512, 6) void gemm_neg(const fp8_t* __restrict__ A,
                                                   const fp8_t* __restrict__ Bm,
                                                   float* __restrict__ S) {
    __shared__ fp8_t Bl[NBUF][BN * BKB];   // 32 KB ring
    gemm_body<0, 4>(A, Bm, S, nullptr, blockIdx.y * BM, blockIdx.x * 4,
                    (int)threadIdx.x, Bl);
}

// ---- gemm1 + finalize (R12-proven last-block arrive). (512,4) known-good. ----
__global__ __launch_bounds__(512, 4) void gemm_pos_fin(
        const fp8_t* __restrict__ A, const fp8_t* __restrict__ Bm,
        float* __restrict__ S, float* __restrict__ lsum,
        const float* __restrict__ csA, const float* __restrict__ csP,
        const float* __restrict__ csN, uint32* __restrict__ cnt,
        float* __restrict__ out) {
    __shared__ fp8_t Bl[NBUF][BN * BKB];
    __shared__ float red[16];
    __shared__ int lastf;

    const int tid  = threadIdx.x;
    const int lane = tid & 63;
    const int w    = tid >> 6;

    gemm_body<1, 2>(A, Bm, S, lsum, blockIdx.y * BM, blockIdx.x * 2, tid, Bl);

    __syncthreads();
    if (tid == 0) {
        __threadfence();
        uint32 p = atomicAdd(cnt, 1u);
        lastf = (p == GRID_POS - 1);
    }
    __syncthreads();
    if (lastf) {
        __threadfence();
        float av = csA[(size_t)tid * CS_STRIDE];
        float dp = av * csP[(size_t)tid * CS_STRIDE];
        float dn = av * csN[(size_t)tid * CS_STRIDE];
#pragma unroll
        for (int off = 1; off < 64; off <<= 1) {
            dp += __shfl_xor(dp, off);
            dn += __shfl_xor(dn, off);
        }
        __syncthreads();
        if (lane == 0) { red[w] = dp; red[8 + w] = dn; }
        __syncthreads();
        if (tid == 0) {
            float sdp = 0.f, sdn = 0.f;
#pragma unroll
            for (int i = 0; i < 8; ++i) { sdp += red[i]; sdn += red[8 + i]; }
            float mean_pos = sdp * INV_T / ((float)B_ROWS * (float)P_ROWS);
            float mean_neg = sdn * INV_T / ((float)B_ROWS * (float)N_ROWS);
            out[0] = lsum[0] / ((float)B_ROWS * (float)P_ROWS);
            out[1] = mean_pos;
            out[2] = mean_neg;
            out[3] = mean_pos - mean_neg;
        }
    }
}

extern "C" void kernel_launch(void* const* d_in, const int* in_sizes, int n_in,
                              void* d_out, int out_size, void* d_ws, size_t ws_size,
                              hipStream_t stream) {
    const float* anc = (const float*)d_in[0];
    const float* pos = (const float*)d_in[1];
    const float* neg = (const float*)d_in[2];
    float* out = (float*)d_out;

    fp8_t* a8 = (fp8_t*)d_ws;
    fp8_t* p8 = a8 + (size_t)B_ROWS * D_DIM;
    fp8_t* n8 = p8 + (size_t)P_ROWS * D_DIM;
    float* fsec = (float*)(n8 + (size_t)N_ROWS * D_DIM);  // 12MB offset, 64B-aligned
    float* S    = fsec;                        // 4096
    float* csA  = S + B_ROWS;                  // 512*16
    float* csP  = csA + D_DIM * CS_STRIDE;     // 512*16
    float* csN  = csP + D_DIM * CS_STRIDE;     // 512*16
    float* lsum = csN + D_DIM * CS_STRIDE;     // 1 (+3 pad)
    uint32* cnt = (uint32*)(lsum + 4);         // arrive counter

    // ws is re-poisoned 0xAA before every launch -> zero accumulators + counter
    (void)hipMemsetAsync(fsec, 0, (B_ROWS + 3 * D_DIM * CS_STRIDE + 8) * sizeof(float), stream);

    norm_colsum<<<1024, 256, 0, stream>>>(anc, pos, neg, a8, p8, n8, csA, csP, csN);

    // gemm0: 1024 blocks (TN=4) -> 3 co-resident blocks/CU (768 slots).
    gemm_neg<<<dim3((N_ROWS / BN) / 4, B_ROWS / BM), 512, 0, stream>>>(a8, n8, S);
    // gemm1+finalize: 512 blocks (TN=2), 2/CU as measured in R9/R12.
    gemm_pos_fin<<<dim3((P_ROWS / BN) / 2, B_ROWS / BM), 512, 0, stream>>>(
        a8, p8, S, lsum, csA, csP, csN, cnt, out);
}